// Round 9
// baseline (264.062 us; speedup 1.0000x reference)
//
#include <hip/hip_runtime.h>
#include <hip/hip_bf16.h>

// LaplaceCostNet — MI355X (gfx950), round 9.
// R8 post-mortem: mlp is dependency-bound through LDS (act round-trips + barriers);
// occupancy gains cancel vs traffic. R9: register-resident activations.
//  - 32x32x16 MFMA; C/D cols = points = lane&31 stay pinned across layers;
//    inter-layer C-layout -> B-layout via ONE shfl_xor(32) per 8-block. No act LDS,
//    no barriers in the batch loop.
//  - Persistent blocks: 256 x 512thr, ALL 4 layers' weights (128 KB) staged once.
//  - A-frags via 2x ds_read_b64 with (chunk + n)&31 swizzle: conflict-free.
//  - Encoding direct into B-frags (HW sin/cos in revolutions).
//
// Workspace (bytes):
//   [4096   .. 135168)   WT bf16, swizzled for DMA: row n, physical 8B-chunk pc
//                        holds logical chunk (pc - n)&31  (k = 4*chunk + e)
//   [262144 .. +1MB)     C    fp32
//   [262144+3MB .. +4MB) Vfin fp32

typedef unsigned short ushort_t;
typedef short short8 __attribute__((ext_vector_type(8)));
typedef float floatx16 __attribute__((ext_vector_type(16)));

#define HH 512
#define WW 512
#define NPIX (HH*WW)

__device__ inline unsigned int pk_bf16(float a, float b) {   // a->low16, b->high16
    __hip_bfloat162 h = __float22bfloat162_rn(float2{a, b});
    return *(unsigned int*)&h;
}
__device__ inline void async_copy16(void* lds, const void* g) {
    __builtin_amdgcn_global_load_lds(
        (const __attribute__((address_space(1))) unsigned int*)g,
        (__attribute__((address_space(3))) unsigned int*)lds, 16, 0, 0);
}

// ---------------- prep: build DMA-ready swizzled WT ----------------
// 16 blocks: l = b>>2, 32-row n-group = b&3. trans = W^T rows (n) x all 128 k.
__global__ __launch_bounds__(256) void prep_kernel(const float* __restrict__ Wh,
                                                   ushort_t* __restrict__ WT) {
    __shared__ float trans[32][129];
    const int t = threadIdx.x;
    const int l = blockIdx.x >> 2, n0 = (blockIdx.x & 3) * 32;
    const int nl = t & 31, k0 = t >> 5;            // k0 0..7
    #pragma unroll
    for (int pass = 0; pass < 16; ++pass) {
        int k = pass * 8 + k0;
        trans[nl][k] = Wh[l * 16384 + k * 128 + n0 + nl];   // coalesced in n
    }
    __syncthreads();
    #pragma unroll
    for (int c = 0; c < 2; ++c) {
        int idx = c * 256 + t;                      // 0..511 : 32 rows x 16 chunks
        int nl2 = idx >> 4, P = idx & 15;
        int n = n0 + nl2;
        unsigned int w[4];
        #pragma unroll
        for (int hb = 0; hb < 2; ++hb) {
            int c8 = (2 * P + hb - n) & 31;         // logical 8B chunk
            int kk = 4 * c8;
            w[hb * 2 + 0] = pk_bf16(trans[nl2][kk],     trans[nl2][kk + 1]);
            w[hb * 2 + 1] = pk_bf16(trans[nl2][kk + 2], trans[nl2][kk + 3]);
        }
        ((uint4*)WT)[(l * 128 + n) * 16 + P] = uint4{w[0], w[1], w[2], w[3]};
    }
}

// ---------------- MLP: persistent, register-resident activations ----------------
__global__ __launch_bounds__(512, 2) void mlp_kernel(const float* __restrict__ x,
                                                     const ushort_t* __restrict__ WT,
                                                     const float* __restrict__ benc,
                                                     const float* __restrict__ wout,
                                                     float* __restrict__ C_ws,
                                                     float* __restrict__ outbuf) {
    __shared__ __align__(16) ushort_t wlds[4 * 128 * 128];   // 128 KB, all layers
    const int tid = threadIdx.x;
    const int lane = tid & 63, wave = tid >> 6;
    const int m = lane & 31, Hh = lane >> 5;        // point-col, k-half

    // stage all 4 layers once: 8192 16B chunks, linear DMA
    #pragma unroll
    for (int c2 = 0; c2 < 16; ++c2) {
        int base = c2 * 512 + wave * 64;            // wave-uniform chunk base
        async_copy16(&wlds[base * 8], (const char*)WT + (base + lane) * 16);
    }
    __syncthreads();                                // drains DMA; ONLY barrier

    #pragma unroll 1
    for (int t = 0; t < 4; ++t) {
        const int p0 = ((t * 256 + blockIdx.x) * 8 + wave) * 32;

        unsigned int frag[8][4];                    // B-frags: k = ks*16 + Hh*8 + j

        // --- encoding straight into B-frags (dims: 0-63 cos, 64-127 sin) ---
        {
            float2 xv = ((const float2*)x)[p0 + m];
            float xq0 = 0.5f + 0.5f * xv.x, xq1 = 0.5f + 0.5f * xv.y;
            #pragma unroll
            for (int ks = 0; ks < 4; ++ks) {
                #pragma unroll
                for (int jp = 0; jp < 4; ++jp) {
                    int f = ks * 16 + Hh * 8 + jp * 2;
                    float4 b = *(const float4*)&benc[2 * f];
                    float t0 = __builtin_amdgcn_fractf(xq0 * b.x + xq1 * b.y);
                    float t1 = __builtin_amdgcn_fractf(xq0 * b.z + xq1 * b.w);
                    frag[ks][jp]     = pk_bf16(__builtin_amdgcn_cosf(t0),
                                               __builtin_amdgcn_cosf(t1));
                    frag[ks + 4][jp] = pk_bf16(__builtin_amdgcn_sinf(t0),
                                               __builtin_amdgcn_sinf(t1));
                }
            }
        }

        floatx16 acc[4];
        #pragma unroll 1
        for (int l = 0; l < 4; ++l) {
            const ushort_t* wl = wlds + l * 16384;
            #pragma unroll
            for (int i = 0; i < 4; ++i) acc[i] = (floatx16)(0.0f);

            #pragma unroll
            for (int ks = 0; ks < 8; ++ks) {
                short8 bf = *(short8*)&frag[ks][0];
                #pragma unroll
                for (int i = 0; i < 4; ++i) {
                    int n = i * 32 + m;
                    int pcl = (4 * ks + 2 * Hh + n) & 31;      // lo 8B chunk
                    int pch = (4 * ks + 2 * Hh + 1 + n) & 31;  // hi 8B chunk
                    union { short8 v; uint2 u[2]; } a;
                    a.u[0] = *(const uint2*)&wl[n * 128 + pcl * 4];
                    a.u[1] = *(const uint2*)&wl[n * 128 + pch * 4];
                    acc[i] = __builtin_amdgcn_mfma_f32_32x32x16_bf16(a.v, bf, acc[i], 0, 0, 0);
                }
            }

            if (l < 3) {
                // C-layout -> next B-frags: relu, pack, ONE shfl_xor(32) per 8-block
                #pragma unroll
                for (int ks = 0; ks < 8; ++ks) {
                    int i = ks >> 1, par = ks & 1;
                    int bk = 4 * (2 * par + Hh);        // keep block regs
                    int bs = 4 * (2 * par + (1 - Hh));  // send block regs
                    unsigned int k0 = pk_bf16(fmaxf(acc[i][bk + 0], 0.0f), fmaxf(acc[i][bk + 1], 0.0f));
                    unsigned int k1 = pk_bf16(fmaxf(acc[i][bk + 2], 0.0f), fmaxf(acc[i][bk + 3], 0.0f));
                    unsigned int s0 = pk_bf16(fmaxf(acc[i][bs + 0], 0.0f), fmaxf(acc[i][bs + 1], 0.0f));
                    unsigned int s1 = pk_bf16(fmaxf(acc[i][bs + 2], 0.0f), fmaxf(acc[i][bs + 3], 0.0f));
                    unsigned int r0 = (unsigned int)__shfl_xor((int)s0, 32);
                    unsigned int r1 = (unsigned int)__shfl_xor((int)s1, 32);
                    frag[ks][0] = Hh ? r0 : k0;
                    frag[ks][1] = Hh ? r1 : k1;
                    frag[ks][2] = Hh ? k0 : r0;
                    frag[ks][3] = Hh ? k1 : r1;
                }
            }
        }

        // final dot: n = i*32 + (r&3) + 8*(r>>2) + 4*Hh, fp32; cross-half combine
        float s = 0.0f;
        #pragma unroll
        for (int i = 0; i < 4; ++i) {
            #pragma unroll
            for (int rq = 0; rq < 4; ++rq) {
                float4 wv = *(const float4*)&wout[i * 32 + rq * 8 + 4 * Hh];
                s += fmaxf(acc[i][rq * 4 + 0], 0.0f) * wv.x
                   + fmaxf(acc[i][rq * 4 + 1], 0.0f) * wv.y
                   + fmaxf(acc[i][rq * 4 + 2], 0.0f) * wv.z
                   + fmaxf(acc[i][rq * 4 + 3], 0.0f) * wv.w;
            }
        }
        s += __shfl_xor(s, 32);
        if (Hh == 0) {
            C_ws[p0 + m] = s;
            outbuf[NPIX + p0 + m] = s;      // output 1: C
        }
    }
}

// ---------------- fused: cost (box5 + Cs + V0) + 5 Jacobi passes ----------------
__global__ __launch_bounds__(256) void fused_solve_kernel(const int* __restrict__ bt,
                                                          const float* __restrict__ bc,
                                                          const float* __restrict__ C_ws,
                                                          float* __restrict__ Vfin) {
    __shared__ float Va[30 * 32];
    __shared__ float Vb[30 * 32];
    __shared__ float Wp[30 * 32];   // free -> Cs (>=0), pinned/out -> -(bc+1)
    const int tid = threadIdx.x;
    const int gx0 = (blockIdx.x & 31) * 16 - 7, gy0 = (blockIdx.x >> 5) * 16 - 7;

    for (int c = tid; c < 30 * 32; c += 256) {
        int li = c >> 5, lj = c & 31;
        int gi = gy0 + li, gj = gx0 + lj;
        float v = 0.0f;
        if (lj < 30 && gi >= 0 && gi < HH && gj >= 0 && gj < WW) {
            int g = gi * WW + gj;
            float b = bc[g];
            if (bt[g] == 1 && b > 0.0f) v = b;
        }
        Va[c] = v;
    }
    __syncthreads();

    for (int c = tid; c < 30 * 32; c += 256) {
        int li = c >> 5, lj = c & 31;
        int gi = gy0 + li, gj = gx0 + lj;
        float w = -1.0f, v0 = 0.0f;
        if (li >= 2 && li < 28 && lj >= 2 && lj < 28 &&
            gi >= 0 && gi < HH && gj >= 0 && gj < WW) {
            int g = gi * WW + gj;
            if (bt[g] == 0) {
                float s = 0.0f;
                #pragma unroll
                for (int di = 0; di < 5; ++di)
                    #pragma unroll
                    for (int dj = 0; dj < 5; ++dj)
                        s += Va[(li + di - 2) * 32 + lj + dj - 2];
                w = fmaxf(C_ws[g], 0.0f) + s * 0.04f;
                v0 = 100.0f;
            } else {
                float b = bc[g];
                w = -b - 1.0f;
                v0 = b;
            }
        }
        Wp[c] = w;
        Vb[c] = v0;
    }
    __syncthreads();

    float* src = Vb;
    float* dst = Va;
    #pragma unroll 1
    for (int t = 0; t < 5; ++t) {
        for (int c = tid; c < 26 * 32; c += 256) {
            int li = 2 + (c >> 5), lj = c & 31;
            if (lj < 2 || lj >= 28) continue;
            float w = Wp[li * 32 + lj];
            float v;
            if (w < 0.0f) {
                v = -w - 1.0f;
            } else {
                int gi = gy0 + li, gj = gx0 + lj;
                int um = (gi > 0)      ? li - 1 : li;
                int dp = (gi < HH - 1) ? li + 1 : li;
                int lm = (gj > 0)      ? lj - 1 : lj;
                int rp = (gj < WW - 1) ? lj + 1 : lj;
                float s = src[um * 32 + lm] + src[um * 32 + lj] + src[um * 32 + rp]
                        + src[li * 32 + lm]                     + src[li * 32 + rp]
                        + src[dp * 32 + lm] + src[dp * 32 + lj] + src[dp * 32 + rp];
                v = s * 0.125f + w;
            }
            dst[li * 32 + lj] = v;
        }
        __syncthreads();
        float* tmp = src; src = dst; dst = tmp;
    }

    {
        int li = 7 + (tid >> 4), lj = 7 + (tid & 15);
        Vfin[(gy0 + li) * WW + gx0 + lj] = src[li * 32 + lj];
    }
}

// ---------------- bilinear grid sample (align_corners, border clamp) ----------------
__global__ void sample_kernel(const float* __restrict__ x,
                              const float* __restrict__ V,
                              float* __restrict__ out) {
    int idx = blockIdx.x * 256 + threadIdx.x;
    float2 g2 = ((const float2*)x)[idx];
    float ix = (g2.x + 1.0f) * 0.5f * 511.0f;
    float iy = (g2.y + 1.0f) * 0.5f * 511.0f;
    ix = fminf(fmaxf(ix, 0.0f), 511.0f);
    iy = fminf(fmaxf(iy, 0.0f), 511.0f);
    int x0 = (int)floorf(ix), y0 = (int)floorf(iy);
    int x1 = min(x0 + 1, 511), y1 = min(y0 + 1, 511);
    float wx = ix - (float)x0, wy = iy - (float)y0;
    float v00 = V[y0 * 512 + x0], v01 = V[y0 * 512 + x1];
    float v10 = V[y1 * 512 + x0], v11 = V[y1 * 512 + x1];
    float v = v00 * (1.0f - wx) * (1.0f - wy) + v01 * wx * (1.0f - wy)
            + v10 * (1.0f - wx) * wy          + v11 * wx * wy;
    out[idx] = v;   // output 0
}

extern "C" void kernel_launch(void* const* d_in, const int* in_sizes, int n_in,
                              void* d_out, int out_size, void* d_ws, size_t ws_size,
                              hipStream_t stream) {
    const float* x    = (const float*)d_in[0];
    const int*   bt   = (const int*)d_in[1];
    const float* bc   = (const float*)d_in[2];
    const float* benc = (const float*)d_in[3];
    const float* Wh   = (const float*)d_in[4];
    const float* wout = (const float*)d_in[5];

    char* ws = (char*)d_ws;
    ushort_t* WT   = (ushort_t*)(ws + 4096);
    float*    C_ws = (float*)(ws + 262144);
    float*    Vfin = (float*)(ws + 262144 + 3 * (1 << 20));
    float*    outp = (float*)d_out;

    prep_kernel<<<16, 256, 0, stream>>>(Wh, WT);
    mlp_kernel<<<256, 512, 0, stream>>>(x, WT, benc, wout, C_ws, outp);
    fused_solve_kernel<<<1024, 256, 0, stream>>>(bt, bc, C_ws, Vfin);
    sample_kernel<<<1024, 256, 0, stream>>>(x, Vfin, outp);
}

// Round 10
// 122.320 us; speedup vs baseline: 2.1588x; 2.1588x over previous
//
#include <hip/hip_runtime.h>
#include <hip/hip_bf16.h>

// LaplaceCostNet — MI355X (gfx950), round 10.
// R9 post-mortem: frag array address-cast + runtime-indexed acc lanes -> scratch
// (WRITE 16.8 MB, VALU 71%, Mfma 7%). R10 = same register-resident structure,
// scratch-proofed:
//  - fragv: uintx4 ext-vectors, constant subscripts, bit_cast into MFMA;
//  - inter-layer transform: constant acc indices + Hh cndmask selects + shfl_xor(32);
//  - A-frag: ONE ds_read_b128 per MFMA, 16B-chunk swizzle pc=(2ks+Hh)^(n&15)
//    (bank-balanced), WT pre-swizzled accordingly.
//
// Workspace (bytes):
//   [4096   .. 135168)   WT bf16: row n, physical 16B chunk P holds logical
//                        chunk P^(n&15)  (logical chunk cc = elems k=8cc..8cc+7)
//   [262144 .. +1MB)     C    fp32
//   [262144+3MB .. +4MB) Vfin fp32

typedef unsigned short ushort_t;
typedef short short8 __attribute__((ext_vector_type(8)));
typedef float floatx16 __attribute__((ext_vector_type(16)));
typedef unsigned int uintx4 __attribute__((ext_vector_type(4)));

#define HH 512
#define WW 512
#define NPIX (HH*WW)

__device__ inline unsigned int pk_bf16(float a, float b) {   // a->low16, b->high16
    __hip_bfloat162 h = __float22bfloat162_rn(float2{a, b});
    return *(unsigned int*)&h;
}
__device__ inline void async_copy16(void* lds, const void* g) {
    __builtin_amdgcn_global_load_lds(
        (const __attribute__((address_space(1))) unsigned int*)g,
        (__attribute__((address_space(3))) unsigned int*)lds, 16, 0, 0);
}

// ---------------- prep: DMA-ready swizzled WT (16B-chunk granularity) ----------------
// 16 blocks: l = b>>2, n0 = (b&3)*32.
__global__ __launch_bounds__(256) void prep_kernel(const float* __restrict__ Wh,
                                                   ushort_t* __restrict__ WT) {
    __shared__ float trans[32][129];
    const int t = threadIdx.x;
    const int l = blockIdx.x >> 2, n0 = (blockIdx.x & 3) * 32;
    const int nl = t & 31, k0 = t >> 5;            // k0 0..7
    #pragma unroll
    for (int pass = 0; pass < 16; ++pass) {
        int k = pass * 8 + k0;
        trans[nl][k] = Wh[l * 16384 + k * 128 + n0 + nl];   // coalesced in n
    }
    __syncthreads();
    #pragma unroll
    for (int c = 0; c < 2; ++c) {
        int idx = c * 256 + t;                      // 0..511 : 32 rows x 16 chunks
        int nl2 = idx >> 4, P = idx & 15;
        int n = n0 + nl2;
        int cc = P ^ (n & 15);                      // logical 16B chunk
        int kk = cc * 8;
        unsigned int w0 = pk_bf16(trans[nl2][kk + 0], trans[nl2][kk + 1]);
        unsigned int w1 = pk_bf16(trans[nl2][kk + 2], trans[nl2][kk + 3]);
        unsigned int w2 = pk_bf16(trans[nl2][kk + 4], trans[nl2][kk + 5]);
        unsigned int w3 = pk_bf16(trans[nl2][kk + 6], trans[nl2][kk + 7]);
        ((uint4*)WT)[(l * 128 + n) * 16 + P] = uint4{w0, w1, w2, w3};
    }
}

// ---------------- MLP: persistent, register-resident activations ----------------
__global__ __launch_bounds__(512, 2) void mlp_kernel(const float* __restrict__ x,
                                                     const ushort_t* __restrict__ WT,
                                                     const float* __restrict__ benc,
                                                     const float* __restrict__ wout,
                                                     float* __restrict__ C_ws,
                                                     float* __restrict__ outbuf) {
    __shared__ __align__(16) ushort_t wlds[4 * 128 * 128];   // 128 KB, all layers
    const int tid = threadIdx.x;
    const int lane = tid & 63, wave = tid >> 6;
    const int m = lane & 31, Hh = lane >> 5;        // point-col, k-half

    // stage all 4 layers once: 8192 16B chunks, linear DMA
    #pragma unroll
    for (int c2 = 0; c2 < 16; ++c2) {
        int base = c2 * 512 + wave * 64;            // wave-uniform chunk base
        async_copy16(&wlds[base * 8], (const char*)WT + (base + lane) * 16);
    }
    __syncthreads();                                // drains DMA; ONLY barrier

    #pragma unroll 1
    for (int t = 0; t < 4; ++t) {
        const int p0 = ((t * 256 + blockIdx.x) * 8 + wave) * 32;

        uintx4 fragv[8];                            // B-frags: k = ks*16 + Hh*8 + j

        // --- encoding straight into B-frags (dims 0-63 cos, 64-127 sin) ---
        {
            float2 xv = ((const float2*)x)[p0 + m];
            float xq0 = 0.5f + 0.5f * xv.x, xq1 = 0.5f + 0.5f * xv.y;
            #pragma unroll
            for (int ks = 0; ks < 4; ++ks) {
                #pragma unroll
                for (int jp = 0; jp < 4; ++jp) {
                    int f = ks * 16 + Hh * 8 + jp * 2;
                    float4 b = *(const float4*)&benc[2 * f];
                    float t0 = __builtin_amdgcn_fractf(xq0 * b.x + xq1 * b.y);
                    float t1 = __builtin_amdgcn_fractf(xq0 * b.z + xq1 * b.w);
                    fragv[ks][jp]     = pk_bf16(__builtin_amdgcn_cosf(t0),
                                                __builtin_amdgcn_cosf(t1));
                    fragv[ks + 4][jp] = pk_bf16(__builtin_amdgcn_sinf(t0),
                                                __builtin_amdgcn_sinf(t1));
                }
            }
        }

        floatx16 acc[4];
        #pragma unroll 1
        for (int l = 0; l < 4; ++l) {
            const ushort_t* wl = wlds + l * 16384;
            #pragma unroll
            for (int i = 0; i < 4; ++i) acc[i] = (floatx16)(0.0f);

            #pragma unroll
            for (int ks = 0; ks < 8; ++ks) {
                short8 bf = __builtin_bit_cast(short8, fragv[ks]);
                #pragma unroll
                for (int i = 0; i < 4; ++i) {
                    int n = i * 32 + m;
                    int cc = 2 * ks + Hh;                      // logical 16B chunk
                    short8 av = *(const short8*)&wl[(n << 7) + ((cc ^ (n & 15)) << 3)];
                    acc[i] = __builtin_amdgcn_mfma_f32_32x32x16_bf16(av, bf, acc[i], 0, 0, 0);
                }
            }

            if (l < 3) {
                // C-layout -> next B-frags. All acc indices CONSTANT; Hh via selects.
                #pragma unroll
                for (int ks = 0; ks < 8; ++ks) {
                    const int i = ks >> 1, par = ks & 1;
                    unsigned int u0 = pk_bf16(fmaxf(acc[i][8 * par + 0], 0.0f),
                                              fmaxf(acc[i][8 * par + 1], 0.0f));
                    unsigned int u1 = pk_bf16(fmaxf(acc[i][8 * par + 2], 0.0f),
                                              fmaxf(acc[i][8 * par + 3], 0.0f));
                    unsigned int u2 = pk_bf16(fmaxf(acc[i][8 * par + 4], 0.0f),
                                              fmaxf(acc[i][8 * par + 5], 0.0f));
                    unsigned int u3 = pk_bf16(fmaxf(acc[i][8 * par + 6], 0.0f),
                                              fmaxf(acc[i][8 * par + 7], 0.0f));
                    unsigned int s0 = Hh ? u0 : u2;     // send block (rq = 2par+(1-Hh))
                    unsigned int s1 = Hh ? u1 : u3;
                    unsigned int k0 = Hh ? u2 : u0;     // keep block (rq = 2par+Hh)
                    unsigned int k1 = Hh ? u3 : u1;
                    unsigned int r0 = (unsigned int)__shfl_xor((int)s0, 32);
                    unsigned int r1 = (unsigned int)__shfl_xor((int)s1, 32);
                    fragv[ks][0] = Hh ? r0 : k0;
                    fragv[ks][1] = Hh ? r1 : k1;
                    fragv[ks][2] = Hh ? k0 : r0;
                    fragv[ks][3] = Hh ? k1 : r1;
                }
            }
        }

        // final dot: n = i*32 + (r&3) + 8*(r>>2) + 4*Hh; cross-half combine
        float s = 0.0f;
        #pragma unroll
        for (int i = 0; i < 4; ++i) {
            #pragma unroll
            for (int rq = 0; rq < 4; ++rq) {
                float4 wv = *(const float4*)&wout[i * 32 + rq * 8 + 4 * Hh];
                s += fmaxf(acc[i][rq * 4 + 0], 0.0f) * wv.x
                   + fmaxf(acc[i][rq * 4 + 1], 0.0f) * wv.y
                   + fmaxf(acc[i][rq * 4 + 2], 0.0f) * wv.z
                   + fmaxf(acc[i][rq * 4 + 3], 0.0f) * wv.w;
            }
        }
        s += __shfl_xor(s, 32);
        if (Hh == 0) {
            C_ws[p0 + m] = s;
            outbuf[NPIX + p0 + m] = s;      // output 1: C
        }
    }
}

// ---------------- fused: cost (box5 + Cs + V0) + 5 Jacobi passes ----------------
__global__ __launch_bounds__(256) void fused_solve_kernel(const int* __restrict__ bt,
                                                          const float* __restrict__ bc,
                                                          const float* __restrict__ C_ws,
                                                          float* __restrict__ Vfin) {
    __shared__ float Va[30 * 32];
    __shared__ float Vb[30 * 32];
    __shared__ float Wp[30 * 32];   // free -> Cs (>=0), pinned/out -> -(bc+1)
    const int tid = threadIdx.x;
    const int gx0 = (blockIdx.x & 31) * 16 - 7, gy0 = (blockIdx.x >> 5) * 16 - 7;

    for (int c = tid; c < 30 * 32; c += 256) {
        int li = c >> 5, lj = c & 31;
        int gi = gy0 + li, gj = gx0 + lj;
        float v = 0.0f;
        if (lj < 30 && gi >= 0 && gi < HH && gj >= 0 && gj < WW) {
            int g = gi * WW + gj;
            float b = bc[g];
            if (bt[g] == 1 && b > 0.0f) v = b;
        }
        Va[c] = v;
    }
    __syncthreads();

    for (int c = tid; c < 30 * 32; c += 256) {
        int li = c >> 5, lj = c & 31;
        int gi = gy0 + li, gj = gx0 + lj;
        float w = -1.0f, v0 = 0.0f;
        if (li >= 2 && li < 28 && lj >= 2 && lj < 28 &&
            gi >= 0 && gi < HH && gj >= 0 && gj < WW) {
            int g = gi * WW + gj;
            if (bt[g] == 0) {
                float s = 0.0f;
                #pragma unroll
                for (int di = 0; di < 5; ++di)
                    #pragma unroll
                    for (int dj = 0; dj < 5; ++dj)
                        s += Va[(li + di - 2) * 32 + lj + dj - 2];
                w = fmaxf(C_ws[g], 0.0f) + s * 0.04f;
                v0 = 100.0f;
            } else {
                float b = bc[g];
                w = -b - 1.0f;
                v0 = b;
            }
        }
        Wp[c] = w;
        Vb[c] = v0;
    }
    __syncthreads();

    float* src = Vb;
    float* dst = Va;
    #pragma unroll 1
    for (int t = 0; t < 5; ++t) {
        for (int c = tid; c < 26 * 32; c += 256) {
            int li = 2 + (c >> 5), lj = c & 31;
            if (lj < 2 || lj >= 28) continue;
            float w = Wp[li * 32 + lj];
            float v;
            if (w < 0.0f) {
                v = -w - 1.0f;
            } else {
                int gi = gy0 + li, gj = gx0 + lj;
                int um = (gi > 0)      ? li - 1 : li;
                int dp = (gi < HH - 1) ? li + 1 : li;
                int lm = (gj > 0)      ? lj - 1 : lj;
                int rp = (gj < WW - 1) ? lj + 1 : lj;
                float s = src[um * 32 + lm] + src[um * 32 + lj] + src[um * 32 + rp]
                        + src[li * 32 + lm]                     + src[li * 32 + rp]
                        + src[dp * 32 + lm] + src[dp * 32 + lj] + src[dp * 32 + rp];
                v = s * 0.125f + w;
            }
            dst[li * 32 + lj] = v;
        }
        __syncthreads();
        float* tmp = src; src = dst; dst = tmp;
    }

    {
        int li = 7 + (tid >> 4), lj = 7 + (tid & 15);
        Vfin[(gy0 + li) * WW + gx0 + lj] = src[li * 32 + lj];
    }
}

// ---------------- bilinear grid sample (align_corners, border clamp) ----------------
__global__ void sample_kernel(const float* __restrict__ x,
                              const float* __restrict__ V,
                              float* __restrict__ out) {
    int idx = blockIdx.x * 256 + threadIdx.x;
    float2 g2 = ((const float2*)x)[idx];
    float ix = (g2.x + 1.0f) * 0.5f * 511.0f;
    float iy = (g2.y + 1.0f) * 0.5f * 511.0f;
    ix = fminf(fmaxf(ix, 0.0f), 511.0f);
    iy = fminf(fmaxf(iy, 0.0f), 511.0f);
    int x0 = (int)floorf(ix), y0 = (int)floorf(iy);
    int x1 = min(x0 + 1, 511), y1 = min(y0 + 1, 511);
    float wx = ix - (float)x0, wy = iy - (float)y0;
    float v00 = V[y0 * 512 + x0], v01 = V[y0 * 512 + x1];
    float v10 = V[y1 * 512 + x0], v11 = V[y1 * 512 + x1];
    float v = v00 * (1.0f - wx) * (1.0f - wy) + v01 * wx * (1.0f - wy)
            + v10 * (1.0f - wx) * wy          + v11 * wx * wy;
    out[idx] = v;   // output 0
}

extern "C" void kernel_launch(void* const* d_in, const int* in_sizes, int n_in,
                              void* d_out, int out_size, void* d_ws, size_t ws_size,
                              hipStream_t stream) {
    const float* x    = (const float*)d_in[0];
    const int*   bt   = (const int*)d_in[1];
    const float* bc   = (const float*)d_in[2];
    const float* benc = (const float*)d_in[3];
    const float* Wh   = (const float*)d_in[4];
    const float* wout = (const float*)d_in[5];

    char* ws = (char*)d_ws;
    ushort_t* WT   = (ushort_t*)(ws + 4096);
    float*    C_ws = (float*)(ws + 262144);
    float*    Vfin = (float*)(ws + 262144 + 3 * (1 << 20));
    float*    outp = (float*)d_out;

    prep_kernel<<<16, 256, 0, stream>>>(Wh, WT);
    mlp_kernel<<<256, 512, 0, stream>>>(x, WT, benc, wout, C_ws, outp);
    fused_solve_kernel<<<1024, 256, 0, stream>>>(bt, bc, C_ws, Vfin);
    sample_kernel<<<1024, 256, 0, stream>>>(x, Vfin, outp);
}